// Round 12
// baseline (336.116 us; speedup 1.0000x reference)
//
#include <hip/hip_runtime.h>

// MHA: cvt fp32->bf16 -> QKV GEMM (128x256, 4 waves x 128x64 tile, 3-slot
//      pipelined, LDS-coalesced epilogue, V transposed) -> MFMA flash attn
// B=2 S=2048 E=2048 NH=16 HD=128 ROTARY=32 base=1e4 NEG_INF=-1e4
#define B_    2
#define S_    2048
#define E_    2048
#define NH_   16
#define HD_   128
#define NQKV_ 6144
#define M_    4096
#define XN_   (M_ * E_)          // 8388608 X elements
#define NPAN  (E_ / 32)          // 64 K-panels of 32

typedef short bf16x8 __attribute__((ext_vector_type(8)));   // 8 bf16 (4 VGPRs)
typedef float f32x4  __attribute__((ext_vector_type(4)));   // MFMA C/D

typedef const __attribute__((address_space(1))) void* gas_t; // global addrspace
typedef __attribute__((address_space(3))) void*       las_t; // LDS addrspace

__device__ inline float b2f(unsigned short u) {
    return __uint_as_float(((unsigned int)u) << 16);
}
__device__ inline unsigned short f2b(float f) {             // RNE f32->bf16
    unsigned int x = __float_as_uint(f);
    x = x + 0x7fffu + ((x >> 16) & 1u);
    return (unsigned short)(x >> 16);
}
__device__ inline unsigned int pk2(float lo, float hi) {
    return (unsigned int)f2b(lo) | ((unsigned int)f2b(hi) << 16);
}

// ---------------------------------------------------------------------------
// Kernel 0: one-shot fp32 -> bf16 of X (8.39M) and W (12.58M) into workspace.
// ---------------------------------------------------------------------------
__global__ __launch_bounds__(256) void cvt_bf16(
    const float* __restrict__ X,
    const float* __restrict__ W,
    unsigned short* __restrict__ O)      // [XN_ of X][W follows]
{
    const long i = (long)(blockIdx.x * 256 + threadIdx.x) * 8;
    const float* src = (i < XN_) ? (X + i) : (W + (i - XN_));
    const float4 a = *(const float4*)(src);
    const float4 b = *(const float4*)(src + 4);
    uint4 o = { pk2(a.x, a.y), pk2(a.z, a.w), pk2(b.x, b.y), pk2(b.z, b.w) };
    *(uint4*)(O + i) = o;
}

// ---------------------------------------------------------------------------
// Kernel 1: QKV = Xb * Wb^T + bias, RoPE fused.
// ROUND-11: wave tile 64x64 -> 128x64 (4 waves of 256 thr, acc[8][4]).
// Round-10 profile: MfmaUtil 36% with LDS/VALU/HBM all <50% = dependency-
// chain-limited lockstep loop. 128x64 waves cut LDS fragment traffic 25%
// (bytes/FLOP ~ 1/Wm+1/Wn) and double MFMA per barrier-pair (16 -> 32
// independent MFMAs = 154-cyc uninterrupted burst). Same 128x256 block,
// 3-slot gload_lds pipeline, XOR k-octet layout, n-slab XCD swizzle.
// Staging: 256 thr -> A panel = 2 calls, B = 4 calls (6/panel);
// vmcnt invariant: after stage(p+2) the loads newer than stage(p+1) are
// exactly 6 -> vmcnt(6) ensures panel p+1 landed. Tail: vmcnt(0).
// WAR: stage(p+2) writes slot (p-1)%3; reads of it were lgkm-consumed
// before iter p-1's closing barrier; stage issues after that barrier.
// VGPR ~200 -> __launch_bounds__(256,2); LDS 72 KiB -> 2 blocks/CU.
// ---------------------------------------------------------------------------
__global__ __launch_bounds__(256, 2) void qkv_gemm(
    const unsigned short* __restrict__ Xb,   // bf16 [4096][2048]
    const unsigned short* __restrict__ Wb,   // bf16 [6144][2048]
    const float* __restrict__ bias,
    unsigned short* __restrict__ qb,
    unsigned short* __restrict__ kb,
    unsigned short* __restrict__ vt)         // bf16 [B][NH][HD][S]
{
    union GS {
        struct {
            unsigned short As[3][128 * 32];  // 24 KiB
            unsigned short Bs[3][256 * 32];  // 48 KiB
        } s;
        unsigned short Eqk[128 * 264];       // 67584 B (epilogue reuse)
        unsigned short Ev [256 * 136];       // 69632 B (epilogue reuse)
    };
    __shared__ __align__(16) GS gs;

    const int t    = threadIdx.x;            // 0..255
    const int lane = t & 63;
    const int w    = t >> 6;                 // 0..3 = n-quarter (64 cols)
    const int quad = (lane >> 4) & 3;
    const int l16  = lane & 15;

    // XCD-aware 2D-locality swizzle (bid&7 = XCD, 768 = 8 * 96):
    // XCD x -> n-slab {3x..3x+2} (W slab 3MB, L2-resident), m streamed.
    const int xcd = (int)blockIdx.x & 7;
    const int j   = (int)blockIdx.x >> 3;    // 0..95
    const int m0  = (j / 3) * 128;           // 0..31 -> 128-row tiles
    const int n0  = (xcd * 3 + (j % 3)) * 256; // 0..23 -> 256-col tiles

    // staging: A panel (128x32=8KB) = 2 calls, B (256x32=16KB) = 4 calls.
    // 16B-unit u -> (row=u>>2, koLDS=u&3); global octet = koLDS^((row>>1)&3).
    auto stageA = [&](int p) {
        const int sl = p % 3;
        const int k0 = p * 32;
        #pragma unroll
        for (int c = 0; c < 2; c++) {
            const int ub  = c * 256 + w * 64;        // wave-uniform base
            const int u   = ub + lane;
            const int row = u >> 2;
            const int ko  = (u & 3) ^ ((row >> 1) & 3);
            __builtin_amdgcn_global_load_lds(
                (gas_t)(Xb + (size_t)(m0 + row) * E_ + k0 + ko * 8),
                (las_t)&gs.s.As[sl][ub * 8], 16, 0, 0);
        }
    };
    auto stageB = [&](int p) {
        const int sl = p % 3;
        const int k0 = p * 32;
        #pragma unroll
        for (int c = 0; c < 4; c++) {
            const int ub  = c * 256 + w * 64;
            const int u   = ub + lane;
            const int row = u >> 2;
            const int ko  = (u & 3) ^ ((row >> 1) & 3);
            __builtin_amdgcn_global_load_lds(
                (gas_t)(Wb + (size_t)(n0 + row) * E_ + k0 + ko * 8),
                (las_t)&gs.s.Bs[sl][ub * 8], 16, 0, 0);
        }
    };

    f32x4 acc[8][4];
    #pragma unroll
    for (int i = 0; i < 8; i++)
        #pragma unroll
        for (int j2 = 0; j2 < 4; j2++)
            #pragma unroll
            for (int r = 0; r < 4; r++) acc[i][j2][r] = 0.0f;

    stageA(0); stageB(0);
    stageA(1); stageB(1);
    asm volatile("s_waitcnt vmcnt(0)" ::: "memory");
    __builtin_amdgcn_s_barrier();

    for (int p = 0; p < NPAN; p++) {
        const int sl = p % 3;
        bf16x8 af[8], bfv[4];

        #pragma unroll
        for (int mf = 0; mf < 8; mf++) {
            const int row = mf * 16 + l16;
            af[mf] = *(const bf16x8*)&gs.s.As[sl][row * 32 + (quad ^ ((row >> 1) & 3)) * 8];
        }
        #pragma unroll
        for (int nf = 0; nf < 4; nf++) {
            const int rb = w * 64 + nf * 16 + l16;
            bfv[nf] = *(const bf16x8*)&gs.s.Bs[sl][rb * 32 + (quad ^ ((rb >> 1) & 3)) * 8];
        }

        if (p + 2 < NPAN) {
            stageA(p + 2); stageB(p + 2);
            asm volatile("s_waitcnt vmcnt(6)" ::: "memory");   // p+1 landed
        } else {
            asm volatile("s_waitcnt vmcnt(0)" ::: "memory");   // tail
        }
        __builtin_amdgcn_s_barrier();
        __builtin_amdgcn_s_setprio(1);
        #pragma unroll
        for (int mf = 0; mf < 8; mf++)
            #pragma unroll
            for (int nf = 0; nf < 4; nf++)
                acc[mf][nf] = __builtin_amdgcn_mfma_f32_16x16x32_bf16(
                    af[mf], bfv[nf], acc[mf][nf], 0, 0, 0);
        __builtin_amdgcn_s_setprio(0);
        __builtin_amdgcn_s_barrier();
    }

    // ---- bias + fused RoPE on registers
    const int which = n0 >> 11;                   // 0=q 1=k 2=v (const/block)

    float bv[4];
    #pragma unroll
    for (int nf = 0; nf < 4; nf++) bv[nf] = bias[n0 + w * 64 + nf * 16 + l16];
    #pragma unroll
    for (int mi = 0; mi < 8; mi++)
        #pragma unroll
        for (int nf = 0; nf < 4; nf++)
            #pragma unroll
            for (int r = 0; r < 4; r++) acc[mi][nf][r] += bv[nf];

    // RoPE: tile spans 2 heads; head-local d<64 quarters are w==0 / w==2.
    // Pairs (d=l16, d+16) live in acc[mi][0] / acc[mi][1] of same thread.
    if ((w & 1) == 0 && which < 2) {
        const float inv = exp2f(-0.83048202372184059f * (float)l16); // 1e4^(-d/16)
        #pragma unroll
        for (int mi = 0; mi < 8; mi++) {
            #pragma unroll
            for (int r = 0; r < 4; r++) {
                const int m = m0 + mi * 16 + quad * 4 + r;
                const int sdx = m & (S_ - 1);
                float c, sn;
                __sincosf((float)sdx * inv, &sn, &c);
                const float u1 = acc[mi][0][r], u2 = acc[mi][1][r];
                acc[mi][0][r] = u1 * c - u2 * sn;
                acc[mi][1][r] = u1 * sn + u2 * c;
            }
        }
    }

    // ---- LDS-staged coalesced stores (main loop's final barrier passed;
    // all As/Bs reads retired -> union reuse safe).
    const int hb = (n0 >> 7) & 15;                // head base of this tile
    const int bb = m0 >> 11;
    const int sb = m0 & (S_ - 1);
    if (which < 2) {
        unsigned short* dst = (which == 0) ? qb : kb;
        unsigned short* E = gs.Eqk;               // [128][264]
        #pragma unroll
        for (int mi = 0; mi < 8; mi++) {
            const int m = mi * 16 + quad * 4;
            #pragma unroll
            for (int nf = 0; nf < 4; nf++) {
                const int col = w * 64 + nf * 16 + l16;
                #pragma unroll
                for (int r = 0; r < 4; r++)
                    E[(m + r) * 264 + col] = f2b(acc[mi][nf][r]);
            }
        }
        __syncthreads();
        const int em   = t >> 1;                  // 0..127
        const int half = t & 1;                   // head within tile
        unsigned short* orow =
            dst + ((size_t)(bb * NH_ + hb + half) * S_ + sb + em) * HD_;
        const unsigned short* erow = &E[em * 264 + half * 128];
        #pragma unroll
        for (int i = 0; i < 16; i++) {            // 16 chunks of 8 bf16
            uint4 vv = *(const uint4*)&erow[i * 8];
            *(uint4*)&orow[i * 8] = vv;
        }
    } else {
        unsigned short* E = gs.Ev;                // [256][136]
        #pragma unroll
        for (int mi = 0; mi < 8; mi++) {
            const int m = mi * 16 + quad * 4;
            #pragma unroll
            for (int nf = 0; nf < 4; nf++) {
                const int col = w * 64 + nf * 16 + l16;
                #pragma unroll
                for (int r = 0; r < 4; r++)
                    E[col * 136 + m + r] = f2b(acc[mi][nf][r]);
            }
        }
        __syncthreads();
        const int col = t;                        // 0..255
        const int hh  = hb + (col >> 7);
        const int d   = col & 127;
        unsigned short* vrow =
            vt + ((size_t)(bb * NH_ + hh) * HD_ + d) * S_ + sb;
        #pragma unroll
        for (int i = 0; i < 16; i++) {            // 128 m-elems = 16 chunks
            uint4 vv = *(const uint4*)&E[col * 136 + i * 8];
            *(uint4*)&vrow[i * 8] = vv;
        }
    }
}

// ---------------------------------------------------------------------------
// Kernel 2: MFMA causal flash attention (BYTE-IDENTICAL to round 10:
// gload_lds double-buffered K/V, one barrier/iter, T5 setprio clusters).
// Layouts (HW-verified 16x16x32_bf16): A[m=lane&15][k=quad*8+j];
// C/D row=quad*4+reg, col=lane&15.
// ---------------------------------------------------------------------------
#define PSTR 72
#define OSTR 132

__global__ __launch_bounds__(256, 2) void attn_mfma(
    const unsigned short* __restrict__ qb,
    const unsigned short* __restrict__ kb,
    const unsigned short* __restrict__ vt,
    float* __restrict__ out)
{
    union SM {
        struct {
            unsigned short Ks[2][64 * 128];    // 32768 B
            unsigned short Vs[2][128 * 64];    // 32768 B
            unsigned short Ps[4 * 16 * PSTR];  //  9216 B
        } a;                                   // 74752 B total
        float Ow[4 * 16 * OSTR];               // 33792 B (epilogue reuse)
    };
    __shared__ __align__(16) SM sm;

    const int bid  = blockIdx.x;
    const int qt   = 31 - (bid >> 5);       // 64-row q-tile, heavy-first
    const int bh   = bid & 31;
    const int b    = bh >> 4;
    const int h    = bh & 15;
    const int t    = threadIdx.x;
    const int lane = t & 63;
    const int w    = t >> 6;
    const int quad = lane >> 4;
    const int l16  = lane & 15;

    const int wrow0  = qt * 64 + w * 16;    // wave q-row base (16 rows)
    const int ntiles = qt + 1;              // K tiles of 64

    unsigned short* Pw = sm.a.Ps + w * 16 * PSTR;

    // staging lane maps: K rows = s (256B each, 16 lanes); V rows = d (128B, 8)
    const int ksrow = w * 4 + (lane >> 4);  // + c*16
    const int ksu   = lane & 15;
    const int vdrow = w * 8 + (lane >> 3);  // + c*32
    const int vsu   = lane & 7;

    auto stage = [&](int kt2, int bsel) {
        const int s2 = kt2 * 64;
        #pragma unroll
        for (int c = 0; c < 4; c++) {
            const int srow = c * 16 + ksrow;
            __builtin_amdgcn_global_load_lds(
                (gas_t)(kb + ((size_t)(bh * S_ + s2 + srow)) * HD_
                        + (ksu ^ (srow & 7)) * 8),
                (las_t)&sm.a.Ks[bsel][(c * 16 + w * 4) * 128], 16, 0, 0);
        }
        #pragma unroll
        for (int c = 0; c < 4; c++) {
            const int drow = c * 32 + vdrow;
            __builtin_amdgcn_global_load_lds(
                (gas_t)(vt + ((size_t)(bh * HD_ + drow)) * S_ + s2
                        + (vsu ^ (drow & 7)) * 8),
                (las_t)&sm.a.Vs[bsel][(c * 32 + w * 8) * 64], 16, 0, 0);
        }
    };

    // Q A-fragments from global: k = c*32 + quad*8 + j
    bf16x8 qf[4];
    {
        const unsigned short* qp =
            qb + ((size_t)(bh * S_ + wrow0 + l16)) * HD_ + quad * 8;
        #pragma unroll
        for (int c = 0; c < 4; c++)
            qf[c] = *(const bf16x8*)(qp + c * 32);
    }

    f32x4 of[8];
    #pragma unroll
    for (int db = 0; db < 8; db++)
        #pragma unroll
        for (int r = 0; r < 4; r++) of[db][r] = 0.0f;
    float mr[4], lr[4];
    #pragma unroll
    for (int r = 0; r < 4; r++) { mr[r] = -1e30f; lr[r] = 0.0f; }

    // log2-domain softmax: scale' = (1/sqrt(128))*log2(e), mask' = -1e4*log2(e)
    const float scale2 = 0.12751744459892879f;
    const float mneg2  = -14426.950408889634f;

    stage(0, 0);
    __syncthreads();                 // vmcnt(0) + barrier: tile 0 landed
    int cur = 0;

    for (int kt = 0; kt < ntiles; kt++) {
        const int s0 = kt * 64;
        if (kt + 1 < ntiles) stage(kt + 1, cur ^ 1);   // hidden under compute

        // ---- S = Q K^T (swizzled kf reads)
        f32x4 sf[4];
        #pragma unroll
        for (int nb = 0; nb < 4; nb++)
            #pragma unroll
            for (int r = 0; r < 4; r++) sf[nb][r] = 0.0f;
        __builtin_amdgcn_s_setprio(1);
        #pragma unroll
        for (int c = 0; c < 4; c++) {
            #pragma unroll
            for (int nb = 0; nb < 4; nb++) {
                const int u = (c * 4 + quad) ^ (l16 & 7);
                bf16x8 kf = *(const bf16x8*)
                    &sm.a.Ks[cur][(nb * 16 + l16) * 128 + u * 8];
                sf[nb] = __builtin_amdgcn_mfma_f32_16x16x32_bf16(
                    qf[c], kf, sf[nb], 0, 0, 0);
            }
        }
        __builtin_amdgcn_s_setprio(0);

        // ---- scale + causal mask, log2 domain
        const bool need_mask = (s0 + 63 > wrow0);
        {
            const int qr0 = wrow0 + quad * 4;
            #pragma unroll
            for (int nb = 0; nb < 4; nb++) {
                const int kcol = s0 + nb * 16 + l16;
                #pragma unroll
                for (int r = 0; r < 4; r++) {
                    float s = sf[nb][r] * scale2;
                    if (need_mask && kcol > qr0 + r) s += mneg2;
                    sf[nb][r] = s;
                }
            }
        }

        // ---- online softmax (16-lane max reduce; lr partials; deferred
        //      rescale when no row max grew)
        {
            float mt4[4];
            #pragma unroll
            for (int r = 0; r < 4; r++) {
                float mt = fmaxf(fmaxf(sf[0][r], sf[1][r]),
                                 fmaxf(sf[2][r], sf[3][r]));
                mt = fmaxf(mt, __shfl_xor(mt, 1));
                mt = fmaxf(mt, __shfl_xor(mt, 2));
                mt = fmaxf(mt, __shfl_xor(mt, 4));
                mt = fmaxf(mt, __shfl_xor(mt, 8));
                mt4[r] = mt;
            }
            const bool grew = (mt4[0] > mr[0]) || (mt4[1] > mr[1]) ||
                              (mt4[2] > mr[2]) || (mt4[3] > mr[3]);
            if (__any(grew)) {
                float alpha[4];
                #pragma unroll
                for (int r = 0; r < 4; r++) {
                    const float mnew = fmaxf(mr[r], mt4[r]);
                    alpha[r] = __builtin_amdgcn_exp2f(mr[r] - mnew);
                    mr[r] = mnew;
                    lr[r] *= alpha[r];
                }
                #pragma unroll
                for (int db = 0; db < 8; db++)
                    #pragma unroll
                    for (int r = 0; r < 4; r++) of[db][r] *= alpha[r];
            }
            #pragma unroll
            for (int r = 0; r < 4; r++) {
                float rs = 0.0f;
                #pragma unroll
                for (int nb = 0; nb < 4; nb++) {
                    float p = __builtin_amdgcn_exp2f(sf[nb][r] - mr[r]);
                    sf[nb][r] = p;
                    rs += p;
                }
                lr[r] += rs;       // per-lane partial; reduced in epilogue
            }

            // P: C-layout -> wave-private LDS [m][s]
            #pragma unroll
            for (int nb = 0; nb < 4; nb++)
                #pragma unroll
                for (int r = 0; r < 4; r++)
                    Pw[(quad * 4 + r) * PSTR + nb * 16 + l16] = f2b(sf[nb][r]);
        }

        // ---- O += P V (swizzled vf reads from row-readable Vs[d][s])
        __builtin_amdgcn_s_setprio(1);
        #pragma unroll
        for (int kc = 0; kc < 2; kc++) {
            bf16x8 pf = *(const bf16x8*)&Pw[l16 * PSTR + kc * 32 + quad * 8];
            #pragma unroll
            for (int db = 0; db < 8; db++) {
                const int u = (kc * 4 + quad) ^ (l16 & 7);
                bf16x8 vf = *(const bf16x8*)
                    &sm.a.Vs[cur][(db * 16 + l16) * 64 + u * 8];
                of[db] = __builtin_amdgcn_mfma_f32_16x16x32_bf16(
                    pf, vf, of[db], 0, 0, 0);
            }
        }
        __builtin_amdgcn_s_setprio(0);

        __syncthreads();           // drains my stage(t+1) + all waves done
        cur ^= 1;
    }

    // ---- epilogue: lane-reduce lr, normalize, LDS transpose, float4 stores.
    float* Ow = sm.Ow + w * 16 * OSTR;     // wave-private 16x132 fp32
    float inv[4];
    #pragma unroll
    for (int r = 0; r < 4; r++) {
        float ls = lr[r];
        ls += __shfl_xor(ls, 1);
        ls += __shfl_xor(ls, 2);
        ls += __shfl_xor(ls, 4);
        ls += __shfl_xor(ls, 8);
        inv[r] = 1.0f / ls;
    }
    #pragma unroll
    for (int db = 0; db < 8; db++)
        #pragma unroll
        for (int r = 0; r < 4; r++)
            Ow[(quad * 4 + r) * OSTR + db * 16 + l16] = of[db][r] * inv[r];
    #pragma unroll
    for (int rg = 0; rg < 4; rg++) {
        const int rowl = rg * 4 + quad;
        float* op = out + ((size_t)(b * S_ + wrow0 + rowl)) * E_ + h * HD_;
        #pragma unroll
        for (int u = 0; u < 2; u++) {
            float4 v4 = *(const float4*)&Ow[rowl * OSTR + u * 64 + l16 * 4];
            *(float4*)(op + u * 64 + l16 * 4) = v4;
        }
    }
}

// ---------------------------------------------------------------------------
extern "C" void kernel_launch(void* const* d_in, const int* in_sizes, int n_in,
                              void* d_out, int out_size, void* d_ws, size_t ws_size,
                              hipStream_t stream)
{
    const float* x    = (const float*)d_in[0];   // fp32 (B,S,E)
    const float* W    = (const float*)d_in[1];   // fp32 (6144,2048)
    const float* bias = (const float*)d_in[2];   // fp32 (6144,)
    float* out = (float*)d_out;                  // fp32 (B,S,E)

    const size_t per = (size_t)B_ * NH_ * S_ * HD_;               // 8388608
    unsigned short* qb = (unsigned short*)d_ws;                   // [B][NH][S][HD]
    unsigned short* kb = qb + per;                                // [B][NH][S][HD]
    unsigned short* vt = kb + per;                                // [B][NH][HD][S]
    unsigned short* Xb = vt + per;                                // bf16 X
    unsigned short* Wb = Xb + (size_t)XN_;                        // bf16 W

    const int cvt_elems = XN_ + NQKV_ * E_;                       // 20971520
    cvt_bf16<<<cvt_elems / (256 * 8), 256, 0, stream>>>(x, W, Xb);

    dim3 gemm_grid((M_ / 128) * (NQKV_ / 256));                   // 32*24 = 768
    qkv_gemm<<<gemm_grid, 256, 0, stream>>>(Xb, Wb, bias, qb, kb, vt);

    attn_mfma<<<dim3(32 * 32), 256, 0, stream>>>(qb, kb, vt, out);
}